// Round 12
// baseline (728.334 us; speedup 1.0000x reference)
//
#include <hip/hip_runtime.h>

typedef unsigned short u16;
typedef u16 u16x8 __attribute__((ext_vector_type(8)));
typedef u16 u16x4 __attribute__((ext_vector_type(4)));
typedef __bf16 bf16x8 __attribute__((ext_vector_type(8)));
typedef float f32x4 __attribute__((ext_vector_type(4)));

#define DEVI static __device__ __forceinline__

DEVI float b2f(u16 u){ union { unsigned u; float f; } c; c.u = ((unsigned)u) << 16; return c.f; }
DEVI u16 f2b(float f){ union { float f; unsigned u; } c; c.f = f;
  unsigned r = c.u + 0x7fffu + ((c.u >> 16) & 1u); return (u16)(r >> 16); }
DEVI void gload16(const void* g, void* l){
  __builtin_amdgcn_global_load_lds((const __attribute__((address_space(1))) void*)g,
                                   (__attribute__((address_space(3))) void*)l, 16, 0, 0);
}
DEVI f32x4 MFMA(bf16x8 a, bf16x8 b, f32x4 c){
  return __builtin_amdgcn_mfma_f32_16x16x32_bf16(a, b, c, 0, 0, 0);
}

// B=2, L=2048, HID=2048, H=16, HKV=8, D=128, CHUNK=64, NC=32, TOK=4096
constexpr size_t OFF_HB  = 0;                                   // h bf16 [4096][2048]
constexpr size_t OFF_WCT = OFF_HB  + (size_t)4096*2048*2;       // WcatT bf16 (Wq|Wk|Wv)^T [4096][2048]
constexpr size_t OFF_WOT = OFF_WCT + (size_t)4224*2048*2;       // WoT bf16 [2048][2048]
constexpr size_t OFF_QKV = OFF_WOT + (size_t)2048*2048*2;       // QKV bf16 [4096][4096]
constexpr size_t OFF_G1  = OFF_QKV + (size_t)4096*4096*2;       // (unused)
constexpr size_t OFF_G   = OFF_G1  + (size_t)4096*16*4;         // g f32 [4096][1024] raw logits
constexpr size_t OFF_EB  = OFF_G   + (size_t)4096*1024*4;       // exp(b) bf16 [4096][1024]
constexpr size_t OFF_KD  = OFF_EB  + (size_t)4096*1024*2;       // k*exp(-b) bf16 [4096][1024]
constexpr size_t OFF_T   = OFF_KD  + (size_t)4096*1024*2;       // T^T bf16 [2][8][32][128 e][128 d]
constexpr size_t OFF_DV  = OFF_T   + (size_t)2*8*32*128*128*2;  // Dvec f32 [2][8][32][128]
constexpr size_t OFF_SP  = OFF_DV  + (size_t)2*8*32*128*4;      // S_prefix bf16 [2][8][32][128 e][128 d]
constexpr size_t OFF_ON  = OFF_SP  + (size_t)2*8*32*128*128*2;  // o_normed bf16 [4096][2048]
constexpr size_t OFF_WTL = OFF_ON  + (size_t)4096*2048*2;       // wtilT bf16 [1024][2048]

// ---------------- fused prep: h->bf16, 4 weight transposes, wtilde ----------------
__global__ __launch_bounds__(256) void k_prep(const float* __restrict__ h, u16* __restrict__ hb,
                                              const float* __restrict__ Wq, const float* __restrict__ Wk,
                                              const float* __restrict__ Wv, const float* __restrict__ Wo,
                                              u16* __restrict__ wct, u16* __restrict__ wot,
                                              const float* __restrict__ Wg1, const float* __restrict__ Wg2,
                                              u16* __restrict__ wt){
  __shared__ float tile[64][65];
  int id = blockIdx.x, t = threadIdx.x;
  if (id < 2048){
    int idx = id*256 + t;
    for (int i = idx; i < 4096*2048/4; i += 2048*256){
      float4 v = ((const float4*)h)[i];
      u16x4 o; o[0]=f2b(v.x); o[1]=f2b(v.y); o[2]=f2b(v.z); o[3]=f2b(v.w);
      ((u16x4*)hb)[i] = o;
    }
    return;
  }
  if (id < 5120){
    const float* src; u16* dst; int N, rowOff, bx, by;
    if (id < 3072){ int lo = id-2048; src = Wq; dst = wct; N = 2048; rowOff = 0;    bx = lo&31; by = lo>>5; }
    else if (id < 3584){ int lo = id-3072; src = Wk; dst = wct; N = 1024; rowOff = 2048; bx = lo&15; by = lo>>4; }
    else if (id < 4096){ int lo = id-3584; src = Wv; dst = wct; N = 1024; rowOff = 3072; bx = lo&15; by = lo>>4; }
    else { int lo = id-4096; src = Wo; dst = wot; N = 2048; rowOff = 0; bx = lo&31; by = lo>>5; }
    int kb = by*64, nb = bx*64;
    int x = t & 63, y0 = t >> 6;
#pragma unroll
    for (int i = 0; i < 16; i++){
      int y = y0 + i*4;
      tile[y][x] = src[(size_t)(kb + y)*N + nb + x];
    }
    __syncthreads();
#pragma unroll
    for (int i = 0; i < 16; i++){
      int y = y0 + i*4;
      dst[(size_t)(rowOff + nb + y)*2048 + kb + x] = f2b(tile[x][y]);
    }
    return;
  }
  __shared__ float w2s[16*8];
  int c0 = (id - 5120)*8;
  if (t < 128){ int j = t>>3, cc = t&7; w2s[j*8+cc] = Wg2[j*1024 + c0 + cc]; }
  __syncthreads();
  int r0 = t*8;
#pragma unroll
  for (int half = 0; half < 2; half++){
    float rowv[4][16];
#pragma unroll
    for (int u = 0; u < 4; u++)
#pragma unroll
      for (int j4 = 0; j4 < 4; j4++)
        *(float4*)&rowv[u][j4*4] = *(const float4*)&Wg1[(size_t)(r0 + half*4 + u)*16 + j4*4];
#pragma unroll
    for (int cc = 0; cc < 8; cc++){
      u16x4 o;
#pragma unroll
      for (int u = 0; u < 4; u++){
        float s = 0.f;
#pragma unroll
        for (int j = 0; j < 16; j++) s += rowv[u][j]*w2s[j*8+cc];
        o[u] = f2b(s);
      }
      *(u16x4*)&wt[(size_t)(c0+cc)*2048 + r0 + half*4] = o;
    }
  }
}

// ---------------- m97-style 128x128 GEMM ----------------
// MODE 0: fused QKV+gate, N=5120, grid 1280, 5 blocks/CU (160KB LDS exactly) -> no tail.
// MODE 1: fp32 out pitch 2048 (grid 512), 4 blocks/CU cap.
template<int MODE>
__global__ __launch_bounds__(256, (MODE==0) ? 5 : 4)
void gemm128(const u16* __restrict__ A, const u16* __restrict__ Bt,
             const u16* __restrict__ BtHi,
             u16* __restrict__ Cq, float* __restrict__ Cf,
             const float* __restrict__ bq, const float* __restrict__ bk,
             const float* __restrict__ bv, const float* __restrict__ bg2){
  constexpr int NT = 64;
  constexpr int NTN = (MODE==0) ? 40 : 16;
  constexpr int CPX = (MODE==0) ? 160 : 64;    // grid/8, bijective
  __shared__ u16 sA[2*128*32];
  __shared__ u16 sB[2*128*32];
  int id = blockIdx.x;
  int swz = (id & 7)*CPX + (id >> 3);
  int mt = swz / NTN, nt = swz % NTN;
  int t = threadIdx.x, w = t >> 6, l = t & 63;
  int wr = w >> 1, wc = w & 1;
  int mRow0 = mt*128, nCol0 = nt*128;
  const u16* Bbase = (MODE==0 && nCol0 >= 4096) ? (BtHi + (size_t)(nCol0-4096)*2048)
                                                : (Bt + (size_t)nCol0*2048);
  const u16* srcA[2]; const u16* srcB[2];
#pragma unroll
  for (int i = 0; i < 2; i++){
    int S = t + i*256, r = S>>2, g = (S&3) ^ ((r>>1)&3);
    srcA[i] = A + (size_t)(mRow0 + r)*2048 + g*8;
    srcB[i] = Bbase + (size_t)r*2048 + g*8;
  }
  auto ISSUE = [&](int T){
    int buf = T & 1;
    u16* dA = sA + buf*4096;
    u16* dB = sB + buf*4096;
#pragma unroll
    for (int i = 0; i < 2; i++) gload16(srcA[i] + T*32, dA + (i*256 + w*64)*8);
#pragma unroll
    for (int i = 0; i < 2; i++) gload16(srcB[i] + T*32, dB + (i*256 + w*64)*8);
  };
  f32x4 acc[4][4] = {};
  ISSUE(0);
  for (int T = 0; T < NT; ++T){
    __syncthreads();
    if (T + 1 < NT) ISSUE(T + 1);
    const u16* bufA = sA + (T&1)*4096;
    const u16* bufB = sB + (T&1)*4096;
    bf16x8 bfr[4], afr[4];
#pragma unroll
    for (int ni = 0; ni < 4; ni++){
      int r = wc*64 + ni*16 + (l&15);
      int p = (l>>4) ^ ((r>>1)&3);
      bfr[ni] = *(const bf16x8*)&bufB[(r*4 + p)*8];
    }
#pragma unroll
    for (int mi = 0; mi < 4; mi++){
      int r = wr*64 + mi*16 + (l&15);
      int p = (l>>4) ^ ((r>>1)&3);
      afr[mi] = *(const bf16x8*)&bufA[(r*4 + p)*8];
    }
    __builtin_amdgcn_s_setprio(1);
#pragma unroll
    for (int mi = 0; mi < 4; mi++)
#pragma unroll
      for (int ni = 0; ni < 4; ni++)
        acc[mi][ni] = MFMA(afr[mi], bfr[ni], acc[mi][ni]);
    __builtin_amdgcn_s_setprio(0);
  }
  int iLoc = (l>>4)*4, jc = l & 15;
  if (MODE == 0){
    int kind = (nt < 16) ? 0 : (nt < 24) ? 1 : (nt < 32) ? 2 : 3;
#pragma unroll
    for (int ni = 0; ni < 4; ni++){
      int n = nCol0 + wc*64 + ni*16 + jc;
      float bias = (kind == 0) ? bq[n] : (kind == 1) ? bk[n - 2048]
                 : (kind == 2) ? bv[n - 3072] : bg2[n - 4096];
#pragma unroll
      for (int mi = 0; mi < 4; mi++){
        int m = mRow0 + wr*64 + mi*16 + iLoc;
#pragma unroll
        for (int rr = 0; rr < 4; rr++){
          float x = acc[mi][ni][rr] + bias;
          int row = m + rr;
          if (kind == 0)      Cq[(size_t)row*4096 + n] = f2b(fmaxf(x, 0.f) * 0.08838834764831845f);
          else if (kind == 1) Cq[(size_t)row*4096 + n] = f2b(fmaxf(x, 0.f));
          else if (kind == 2) Cq[(size_t)row*4096 + n] = f2b(x);
          else                Cf[(size_t)row*1024 + (n - 4096)] = x;
        }
      }
    }
  } else {
#pragma unroll
    for (int ni = 0; ni < 4; ni++){
      int n = nCol0 + wc*64 + ni*16 + jc;
#pragma unroll
      for (int mi = 0; mi < 4; mi++){
        int m = mRow0 + wr*64 + mi*16 + iLoc;
#pragma unroll
        for (int rr = 0; rr < 4; rr++) Cf[(size_t)(m+rr)*2048 + n] = acc[mi][ni][rr];
      }
    }
  }
}

// ---------------- phase A: logsigmoid, cumsum, eb, kd, T^T = v^T @ kend ----------------
__global__ __launch_bounds__(256) void k_phaseA(const float* __restrict__ g, const u16* __restrict__ QKV,
                                                u16* __restrict__ eb, u16* __restrict__ kd,
                                                u16* __restrict__ T, float* __restrict__ Dv){
  __shared__ float gb[64*128];
  __shared__ u16 keT[128*72];
  __shared__ u16 vT [128*72];
  int c = blockIdx.x, kvh = blockIdx.y, b = blockIdx.z;
  int t = threadIdx.x;
  int tok0 = b*2048 + c*64;
#pragma unroll
  for (int r = 0; r < 8; r++){
    int idx4 = r*256 + t;
    int i = idx4 >> 5, c4 = idx4 & 31;
    float4 v = *(const float4*)&g[(size_t)(tok0+i)*1024 + kvh*128 + c4*4];
    float4 o;
    o.x = (fminf(v.x,0.f) - log1pf(expf(-fabsf(v.x)))) * 0.0625f;
    o.y = (fminf(v.y,0.f) - log1pf(expf(-fabsf(v.y)))) * 0.0625f;
    o.z = (fminf(v.z,0.f) - log1pf(expf(-fabsf(v.z)))) * 0.0625f;
    o.w = (fminf(v.w,0.f) - log1pf(expf(-fabsf(v.w)))) * 0.0625f;
    ((float4*)gb)[i*32 + c4] = o;
  }
  __syncthreads();
  if (t < 128){
    float run = 0.f;
#pragma unroll
    for (int i = 0; i < 64; i++){ run += gb[i*128 + t]; gb[i*128 + t] = run; }
    Dv[((size_t)(b*8+kvh)*32 + c)*128 + t] = expf(run);
  }
  __syncthreads();
  int d0 = (t&15)*8;
  float blast[8];
#pragma unroll
  for (int j = 0; j < 8; j++) blast[j] = gb[63*128 + d0 + j];
#pragma unroll
  for (int r = 0; r < 4; r++){
    int i = (t>>4) + r*16;
    u16x8 kv_ = *(const u16x8*)&QKV[(size_t)(tok0+i)*4096 + 2048 + kvh*128 + d0];
    u16x8 vv  = *(const u16x8*)&QKV[(size_t)(tok0+i)*4096 + 3072 + kvh*128 + d0];
    u16x8 ebv, kdv;
#pragma unroll
    for (int j = 0; j < 8; j++){
      float bcur = gb[i*128 + d0 + j];
      float kf = b2f(kv_[j]);
      ebv[j] = f2b(expf(bcur));
      kdv[j] = f2b(kf * expf(-bcur));
      keT[(d0+j)*72 + i] = f2b(kf * expf(blast[j] - bcur));
      vT [(d0+j)*72 + i] = vv[j];
    }
    *(u16x8*)&eb[(size_t)(tok0+i)*1024 + kvh*128 + d0] = ebv;
    *(u16x8*)&kd[(size_t)(tok0+i)*1024 + kvh*128 + d0] = kdv;
  }
  __syncthreads();
  int w = t>>6, l = t&63;
  f32x4 acc[2][8] = {};
#pragma unroll
  for (int ks = 0; ks < 2; ks++){
    bf16x8 af[2];
#pragma unroll
    for (int te = 0; te < 2; te++)
      af[te] = *(const bf16x8*)&vT[(w*32 + te*16 + (l&15))*72 + ks*32 + (l>>4)*8];
#pragma unroll
    for (int td = 0; td < 8; td++){
      bf16x8 bf_ = *(const bf16x8*)&keT[(td*16 + (l&15))*72 + ks*32 + (l>>4)*8];
#pragma unroll
      for (int te = 0; te < 2; te++) acc[te][td] = MFMA(af[te], bf_, acc[te][td]);
    }
  }
  size_t tbase = ((size_t)(b*8+kvh)*32 + c)*16384;
#pragma unroll
  for (int te = 0; te < 2; te++)
#pragma unroll
    for (int td = 0; td < 8; td++)
#pragma unroll
      for (int rr = 0; rr < 4; rr++){
        int e = w*32 + te*16 + (l>>4)*4 + rr, d = td*16 + (l&15);
        T[tbase + e*128 + d] = f2b(acc[te][td][rr]);
      }
}

// ---------------- phase B: elementwise scan (128 thr, grid (16,8,2)) ----------------
__global__ __launch_bounds__(128) void k_phaseB(const u16* __restrict__ T, const float* __restrict__ Dv,
                                                u16* __restrict__ SP){
  int kvh = blockIdx.y, b = blockIdx.z;
  int t = threadIdx.x;
  int e = blockIdx.x*8 + (t >> 4);
  int d0 = (t & 15)*8;
  size_t base = ((size_t)(b*8 + kvh)*32)*16384 + (size_t)e*128 + d0;
  size_t dvb  = ((size_t)(b*8 + kvh)*32)*128 + d0;
  float S[8] = {0,0,0,0,0,0,0,0};
#pragma unroll 4
  for (int c = 0; c < 32; c++){
    u16x8 tv = *(const u16x8*)&T[base + (size_t)c*16384];
    float4 dva = *(const float4*)&Dv[dvb + (size_t)c*128];
    float4 dvbv = *(const float4*)&Dv[dvb + (size_t)c*128 + 4];
    u16x8 o;
#pragma unroll
    for (int j = 0; j < 8; j++) o[j] = f2b(S[j]);
    *(u16x8*)&SP[base + (size_t)c*16384] = o;
    float dv[8] = {dva.x, dva.y, dva.z, dva.w, dvbv.x, dvbv.y, dvbv.z, dvbv.w};
#pragma unroll
    for (int j = 0; j < 8; j++) S[j] = S[j]*dv[j] + b2f(tv[j]);
  }
}

// ---------------- phase C: both heads per kv-head (shared kl/vT staging) ----------------
__global__ __launch_bounds__(256) void k_phaseC(const u16* __restrict__ QKV, const u16* __restrict__ eb,
                                                const u16* __restrict__ kd, const u16* __restrict__ SP,
                                                const float* __restrict__ gnw, u16* __restrict__ onrm){
  __shared__ u16 kl[64*128];
  __shared__ u16 sl[64*72];
  __shared__ u16 vT[128*72];
  int c = blockIdx.x, kvh = blockIdx.y, b = blockIdx.z;
  int t = threadIdx.x, w = t>>6, l = t&63;
  int tok0 = b*2048 + c*64;
#pragma unroll
  for (int is = 0; is < 4; is++){
    int row = (t>>4) + is*16;
    int d0s = 8*((t&15) ^ (row&7));
    gload16(&kd[(size_t)(tok0+row)*1024 + kvh*128 + d0s], &kl[is*2048 + w*512]);
  }
  int d0v = (t&15)*8;
#pragma unroll
  for (int r = 0; r < 4; r++){
    int i = (t>>4) + r*16;
    u16x8 vv = *(const u16x8*)&QKV[(size_t)(tok0+i)*4096 + 3072 + kvh*128 + d0v];
#pragma unroll
    for (int jj = 0; jj < 8; jj++) vT[(d0v+jj)*72 + i] = vv[jj];
  }
  u16x8 evv[4];
  {
    int i = w*16 + (l&15);
#pragma unroll
    for (int kt = 0; kt < 4; kt++){
      int dq = kt*32 + (l>>4)*8;
      evv[kt] = *(const u16x8*)&eb[(size_t)(tok0+i)*1024 + kvh*128 + dq];
    }
  }
  float gw[8];
#pragma unroll
  for (int et = 0; et < 8; et++) gw[et] = gnw[et*16 + (l&15)];
  size_t spb = ((size_t)(b*8+kvh)*32 + c)*16384;
  __syncthreads();
  for (int h2 = 0; h2 < 2; h2++){
    int h = kvh*2 + h2;
    bf16x8 aq[4];
    {
      int i = w*16 + (l&15);
#pragma unroll
      for (int kt = 0; kt < 4; kt++){
        int dq = kt*32 + (l>>4)*8;
        u16x8 qv = *(const u16x8*)&QKV[(size_t)(tok0+i)*4096 + h*128 + dq];
        u16x8 o;
#pragma unroll
        for (int jj = 0; jj < 8; jj++) o[jj] = f2b(b2f(qv[jj]) * b2f(evv[kt][jj]));
        aq[kt] = __builtin_bit_cast(bf16x8, o);
      }
    }
    f32x4 accs[4] = {};
#pragma unroll
    for (int kt = 0; kt < 4; kt++){
#pragma unroll
      for (int jt = 0; jt < 4; jt++){
        int j = jt*16 + (l&15);
        int byte_ = j*256 + ((2*(kt*32 + (l>>4)*8)) ^ ((j&7)<<4));
        bf16x8 bk_ = *(const bf16x8*)((const char*)kl + byte_);
        accs[jt] = MFMA(aq[kt], bk_, accs[jt]);
      }
    }
#pragma unroll
    for (int jt = 0; jt < 4; jt++)
#pragma unroll
      for (int rr = 0; rr < 4; rr++){
        int i = w*16 + (l>>4)*4 + rr;
        int j = jt*16 + (l&15);
        sl[i*72 + j] = f2b((i >= j) ? accs[jt][rr] : 0.f);
      }
    f32x4 acco[8] = {};
#pragma unroll
    for (int kt = 0; kt < 4; kt++){
#pragma unroll
      for (int et = 0; et < 8; et++){
        int e = et*16 + (l&15);
        int dd = kt*32 + (l>>4)*8;
        bf16x8 bs = *(const bf16x8*)&SP[spb + (size_t)e*128 + dd];
        acco[et] = MFMA(aq[kt], bs, acco[et]);
      }
    }
    __syncthreads();
#pragma unroll
    for (int kt2 = 0; kt2 < 2; kt2++){
      int i = w*16 + (l&15);
      bf16x8 as = *(const bf16x8*)&sl[i*72 + kt2*32 + (l>>4)*8];
#pragma unroll
      for (int et = 0; et < 8; et++){
        bf16x8 bv_ = *(const bf16x8*)&vT[(et*16 + (l&15))*72 + kt2*32 + (l>>4)*8];
        acco[et] = MFMA(as, bv_, acco[et]);
      }
    }
#pragma unroll
    for (int rr = 0; rr < 4; rr++){
      int i = w*16 + (l>>4)*4 + rr;
      float ss = 0.f;
#pragma unroll
      for (int et = 0; et < 8; et++){ float x = acco[et][rr]; ss += x*x; }
      ss += __shfl_xor(ss, 1); ss += __shfl_xor(ss, 2);
      ss += __shfl_xor(ss, 4); ss += __shfl_xor(ss, 8);
      float sc = rsqrtf(ss*(1.f/128.f) + 1e-5f);
#pragma unroll
      for (int et = 0; et < 8; et++){
        int e = et*16 + (l&15);
        onrm[(size_t)(tok0+i)*2048 + h*128 + e] = f2b(acco[et][rr]*sc*gw[et]);
      }
    }
    __syncthreads();
  }
}

extern "C" void kernel_launch(void* const* d_in, const int* in_sizes, int n_in,
                              void* d_out, int out_size, void* d_ws, size_t ws_size,
                              hipStream_t stream){
  (void)in_sizes; (void)n_in; (void)out_size; (void)ws_size;
  const float* h   = (const float*)d_in[0];
  const float* Wq  = (const float*)d_in[1];
  const float* bq  = (const float*)d_in[2];
  const float* Wk  = (const float*)d_in[3];
  const float* bk  = (const float*)d_in[4];
  const float* Wv  = (const float*)d_in[5];
  const float* bv  = (const float*)d_in[6];
  const float* Wg1 = (const float*)d_in[7];
  const float* Wg2 = (const float*)d_in[8];
  const float* bg2 = (const float*)d_in[9];
  const float* gnw = (const float*)d_in[10];
  const float* Wo  = (const float*)d_in[11];
  float* out = (float*)d_out;
  char* ws = (char*)d_ws;
  u16*   hb   = (u16*)  (ws + OFF_HB);
  u16*   wct  = (u16*)  (ws + OFF_WCT);
  u16*   wot  = (u16*)  (ws + OFF_WOT);
  u16*   qkv  = (u16*)  (ws + OFF_QKV);
  float* gbuf = (float*)(ws + OFF_G);
  u16*   ebuf = (u16*)  (ws + OFF_EB);
  u16*   kdb  = (u16*)  (ws + OFF_KD);
  u16*   Tb   = (u16*)  (ws + OFF_T);
  float* Dvb  = (float*)(ws + OFF_DV);
  u16*   SPb  = (u16*)  (ws + OFF_SP);
  u16*   onb  = (u16*)  (ws + OFF_ON);
  u16*   wtilT= (u16*)  (ws + OFF_WTL);

  k_prep<<<5248, 256, 0, stream>>>(h, hb, Wq, Wk, Wv, Wo, wct, wot, Wg1, Wg2, wtilT);
  gemm128<0><<<1280, 256, 0, stream>>>(hb, wct, wtilT, qkv, gbuf, bq, bk, bv, bg2);
  k_phaseA<<<dim3(32,8,2), 256, 0, stream>>>(gbuf, qkv, ebuf, kdb, Tb, Dvb);
  k_phaseB<<<dim3(16,8,2), 128, 0, stream>>>(Tb, Dvb, SPb);
  k_phaseC<<<dim3(32,8,2), 256, 0, stream>>>(qkv, ebuf, kdb, SPb, gnw, onb);
  gemm128<1><<<512, 256, 0, stream>>>(onb, wot, nullptr, nullptr, out, nullptr, nullptr, nullptr, nullptr);
}